// Round 1
// baseline (1615.314 us; speedup 1.0000x reference)
//
#include <hip/hip_runtime.h>
#include <hip/hip_bf16.h>

#define BB 512
#define SS 1024
#define NI 20
#define HH 64
#define NG 256  // 4*H

typedef unsigned short u16;
typedef unsigned int u32;

__device__ __forceinline__ float bf2f(u16 b) { return __uint_as_float(((u32)b) << 16); }
// mode==1: data is bf16; mode==0: data is fp32
__device__ __forceinline__ float ldw(const void* p, int idx, int mode) {
  return mode ? bf2f(((const u16*)p)[idx]) : ((const float*)p)[idx];
}
__device__ __forceinline__ float frcp(float x) { return __builtin_amdgcn_rcpf(x); }
__device__ __forceinline__ float sigf(float x) { return frcp(1.f + __expf(-x)); }
__device__ __forceinline__ float tanhf_(float x) {
  float e = __expf(2.f * x);           // overflow -> inf -> rcp -> 0 -> +1; underflow -> 0 -> -1
  return 1.f - 2.f * frcp(e + 1.f);
}

// ---- dtype probe: read b_f (256 elems) as bf16; fp32 data produces wild exponents ----
__global__ void probe_kernel(const void* bvec, int* mode) {
  const u16* p = (const u16*)bvec;
  int m = 1;
  for (int i = 0; i < 256; ++i) {
    float v = bf2f(p[i]);
    if (!(fabsf(v) < 1000.0f)) { m = 0; break; }  // catches NaN/inf/huge too
  }
  *mode = m;
}

// ---- tokens + lengths from one-hot input ----
__global__ void tok_kernel(const void* in1, const int* mode_p, short* toks, int* lens) {
  int b = blockIdx.x;
  int t = threadIdx.x;
  int mode = *mode_p;
  int cnt = 0;
  if (mode) {
    for (int q = 0; q < 4; ++q) {
      int s = t + q * 256;
      const u32* r = (const u32*)in1 + (size_t)(b * SS + s) * 10;  // 2 bf16 per u32
      int tok = -1;
#pragma unroll
      for (int w = 0; w < 10; ++w) {
        u32 u = r[w];
        if (u & 0xFFFFu) tok = 2 * w;
        if (u >> 16)     tok = 2 * w + 1;
      }
      toks[b * SS + s] = (short)tok;
      cnt += (tok >= 0);
    }
  } else {
    for (int q = 0; q < 4; ++q) {
      int s = t + q * 256;
      const float4* r = (const float4*)((const float*)in1 + (size_t)(b * SS + s) * 20);
      int tok = -1;
#pragma unroll
      for (int w = 0; w < 5; ++w) {
        float4 u = r[w];
        if (u.x != 0.f) tok = 4 * w;
        if (u.y != 0.f) tok = 4 * w + 1;
        if (u.z != 0.f) tok = 4 * w + 2;
        if (u.w != 0.f) tok = 4 * w + 3;
      }
      toks[b * SS + s] = (short)tok;
      cnt += (tok >= 0);
    }
  }
  __shared__ int red[256];
  red[t] = cnt;
  __syncthreads();
  for (int stp = 128; stp > 0; stp >>= 1) {
    if (t < stp) red[t] += red[t + stp];
    __syncthreads();
  }
  if (t == 0) lens[b] = red[0];
}

// ---- BiLSTM: 1 block = (batch, dir); 4 waves = gate types i,f,g,o; lane j = unit j ----
__global__ __launch_bounds__(256, 4)
void lstm_kernel(const void* Wih_f, const void* Whh_f, const void* b_f,
                 const void* Wih_b, const void* Whh_b, const void* b_b,
                 const int* mode_p, const short* toks, float* hout) {
  int bd = blockIdx.x;
  int b = bd & (BB - 1);
  int dir = bd >> 9;
  int t = threadIdx.x;   // gate index 0..255
  int j = t & 63;        // unit
  int mode = *mode_p;
  const void* Wih = dir ? Wih_b : Wih_f;
  const void* Whh = dir ? Whh_b : Whh_f;
  const void* bv  = dir ? b_b   : b_f;

  __shared__ float wih_t[NI * NG];   // W_ih transposed: [tok][gate], fp32
  __shared__ short tok_s[SS];
  __shared__ float g_lds[2][NG];

#pragma unroll
  for (int i = 0; i < NI; ++i)
    wih_t[i * NG + t] = ldw(Wih, t * NI + i, mode);
  for (int s = t; s < SS; s += 256)
    tok_s[s] = toks[b * SS + s];

  float wreg[HH];
#pragma unroll
  for (int k = 0; k < HH; ++k)
    wreg[k] = ldw(Whh, t * HH + k, mode);
  float bia = ldw(bv, t, mode);
  __syncthreads();

  float h = 0.f, c = 0.f;  // unit-j state, replicated identically in all 4 waves
  int p = 0;
  for (int s = 0; s < SS; ++s) {
    int pos = dir ? (SS - 1 - s) : s;
    int tok = tok_s[pos];
    float acc = bia;
    if (tok >= 0) acc += wih_t[tok * NG + t];
#pragma unroll
    for (int k = 0; k < HH; ++k) {
      float hk = __int_as_float(__builtin_amdgcn_readlane(__float_as_int(h), k));
      acc = fmaf(hk, wreg[k], acc);
    }
    g_lds[p][t] = acc;
    __syncthreads();
    float gi = g_lds[p][j];
    float gf = g_lds[p][64 + j];
    float gg = g_lds[p][128 + j];
    float go = g_lds[p][192 + j];
    float ci = sigf(gi), cf = sigf(gf), cg = tanhf_(gg), co = sigf(go);
    c = cf * c + ci * cg;
    h = co * tanhf_(c);
    p ^= 1;
  }
  if (t < 64)
    hout[b * 128 + dir * 64 + j] = h;
}

// ---- conv path + FC head + softmax; 1 block = 1 batch ----
__global__ void head_kernel(const void* conv1_w, const void* conv2_w, const void* conv2_b,
                            const void* fc1_w, const void* fc1_b,
                            const void* fc2_w, const void* fc2_b,
                            const int* mode_p, const short* toks, const int* lens,
                            const float* hout, void* out) {
  int b = blockIdx.x;
  int t = threadIdx.x;  // 128 threads
  int mode = *mode_p;
  __shared__ float c1w[400];
  __shared__ short tok_s[SS];
  __shared__ float avg[80];
  __shared__ float merged[228];
  __shared__ float fc1v[64];

  for (int i = t; i < 400; i += 128) c1w[i] = ldw(conv1_w, i, mode);
  for (int s = t; s < SS; s += 128) tok_s[s] = toks[b * SS + s];
  __syncthreads();

  int len = lens[b];
  int bw = len >> 2;
  if (t < 80) {
    int k = t / 20, cc = t % 20;
    float sum = 0.f;
    for (int s = k * bw; s < (k + 1) * bw; ++s) {
      // faithful torch reshape: c1r[b,s,cc] lives at flat f = s*20+cc of the [20,1024] map
      int f = s * 20 + cc;
      int ch = f >> 10;
      int pos = f & 1023;
      int tk = tok_s[pos];
      if (tk >= 0) sum += c1w[ch * 20 + tk];  // pos >= len -> zero row -> contributes 0
    }
    avg[t] = sum / (float)bw;
  }
  __syncthreads();

  merged[t] = hout[b * 128 + t];  // [h_fw | h_bw]
  if (t < 100) {
    float dot = ldw(conv2_b, t, mode);
#pragma unroll
    for (int q = 0; q < 80; ++q)
      dot += avg[q] * ldw(conv2_w, t * 80 + q, mode);
    merged[128 + t] = dot > 0.f ? dot : 0.f;  // relu
  }
  __syncthreads();

  if (t < 64) {
    float v = ldw(fc1_b, t, mode);
    for (int m = 0; m < 228; ++m)
      v += merged[m] * ldw(fc1_w, t * 228 + m, mode);
    fc1v[t] = v;   // no activation on fc1 per reference
  }
  __syncthreads();

  if (t == 0) {
    float x0 = ldw(fc2_b, 0, mode), x1 = ldw(fc2_b, 1, mode);
    for (int m = 0; m < 64; ++m) {
      x0 += fc1v[m] * ldw(fc2_w, m, mode);
      x1 += fc1v[m] * ldw(fc2_w, 64 + m, mode);
    }
    float mx = fmaxf(x0, x1);
    float e0 = __expf(x0 - mx), e1 = __expf(x1 - mx);
    float inv = 1.f / (e0 + e1);
    if (mode) {
      ((__hip_bfloat16*)out)[b * 2 + 0] = __float2bfloat16(e0 * inv);
      ((__hip_bfloat16*)out)[b * 2 + 1] = __float2bfloat16(e1 * inv);
    } else {
      ((float*)out)[b * 2 + 0] = e0 * inv;
      ((float*)out)[b * 2 + 1] = e1 * inv;
    }
  }
}

extern "C" void kernel_launch(void* const* d_in, const int* in_sizes, int n_in,
                              void* d_out, int out_size, void* d_ws, size_t ws_size,
                              hipStream_t stream) {
  (void)in_sizes; (void)n_in; (void)out_size; (void)ws_size;
  char* ws = (char*)d_ws;
  int*   mode_p = (int*)ws;                                   // 4 B
  int*   lens   = (int*)(ws + 256);                           // 2 KB
  short* toks   = (short*)(ws + 256 + 2048);                  // 1 MB
  float* hout   = (float*)(ws + 256 + 2048 + (size_t)BB * SS * sizeof(short)); // 256 KB

  probe_kernel<<<1, 1, 0, stream>>>(d_in[3], mode_p);
  tok_kernel<<<BB, 256, 0, stream>>>(d_in[0], mode_p, toks, lens);
  lstm_kernel<<<2 * BB, 256, 0, stream>>>(d_in[1], d_in[2], d_in[3],
                                          d_in[4], d_in[5], d_in[6],
                                          mode_p, toks, hout);
  head_kernel<<<BB, 128, 0, stream>>>(d_in[7], d_in[8], d_in[9],
                                      d_in[10], d_in[11], d_in[12], d_in[13],
                                      mode_p, toks, lens, hout, d_out);
}

// Round 2
// 743.934 us; speedup vs baseline: 2.1713x; 2.1713x over previous
//
#include <hip/hip_runtime.h>
#include <hip/hip_bf16.h>

#define BB 512
#define SS 1024
#define NI 20
#define HH 64
#define NG 256  // 4*H
#define MB 16   // batches per block

typedef unsigned short u16;
typedef unsigned int u32;
typedef _Float16 f16;
typedef f16 f16x8 __attribute__((ext_vector_type(8)));
typedef float f32x4 __attribute__((ext_vector_type(4)));

__device__ __forceinline__ float bf2f(u16 b) { return __uint_as_float(((u32)b) << 16); }
// mode==1: data is bf16; mode==0: data is fp32
__device__ __forceinline__ float ldw(const void* p, int idx, int mode) {
  return mode ? bf2f(((const u16*)p)[idx]) : ((const float*)p)[idx];
}
__device__ __forceinline__ float frcp(float x) { return __builtin_amdgcn_rcpf(x); }
__device__ __forceinline__ float sigf(float x) { return frcp(1.f + __expf(-x)); }
__device__ __forceinline__ float tanhf_(float x) {
  float e = __expf(2.f * x);           // overflow -> inf -> rcp -> 0 -> +1; underflow -> 0 -> -1
  return 1.f - 2.f * frcp(e + 1.f);
}

// ---- dtype probe: read b_f (256 elems) as bf16; fp32 data produces wild exponents ----
__global__ void probe_kernel(const void* bvec, int* mode) {
  const u16* p = (const u16*)bvec;
  int m = 1;
  for (int i = 0; i < 256; ++i) {
    float v = bf2f(p[i]);
    if (!(fabsf(v) < 1000.0f)) { m = 0; break; }  // catches NaN/inf/huge too
  }
  *mode = m;
}

// ---- tokens + lengths from one-hot input ----
__global__ void tok_kernel(const void* in1, const int* mode_p, short* toks, int* lens) {
  int b = blockIdx.x;
  int t = threadIdx.x;
  int mode = *mode_p;
  int cnt = 0;
  if (mode) {
    for (int q = 0; q < 4; ++q) {
      int s = t + q * 256;
      const u32* r = (const u32*)in1 + (size_t)(b * SS + s) * 10;  // 2 bf16 per u32
      int tok = -1;
#pragma unroll
      for (int w = 0; w < 10; ++w) {
        u32 u = r[w];
        if (u & 0xFFFFu) tok = 2 * w;
        if (u >> 16)     tok = 2 * w + 1;
      }
      toks[b * SS + s] = (short)tok;
      cnt += (tok >= 0);
    }
  } else {
    for (int q = 0; q < 4; ++q) {
      int s = t + q * 256;
      const float4* r = (const float4*)((const float*)in1 + (size_t)(b * SS + s) * 20);
      int tok = -1;
#pragma unroll
      for (int w = 0; w < 5; ++w) {
        float4 u = r[w];
        if (u.x != 0.f) tok = 4 * w;
        if (u.y != 0.f) tok = 4 * w + 1;
        if (u.z != 0.f) tok = 4 * w + 2;
        if (u.w != 0.f) tok = 4 * w + 3;
      }
      toks[b * SS + s] = (short)tok;
      cnt += (tok >= 0);
    }
  }
  __shared__ int red[256];
  red[t] = cnt;
  __syncthreads();
  for (int stp = 128; stp > 0; stp >>= 1) {
    if (t < stp) red[t] += red[t + stp];
    __syncthreads();
  }
  if (t == 0) lens[b] = red[0];
}

// ---- BiLSTM via MFMA: block = (dir, 16-batch tile); 4 waves; wave w owns units 16w..16w+15 ----
// Gates for step s: G[16 x 256] = [h(64) | onehot(32)] @ [W_hh^T ; W_ih^T] + bias, via
// 16x16x32 f16 MFMA. Wave w takes N-tiles {w,4+w,8+w,12+w} = gate types i,f,g,o for the
// SAME 16 units -> C-layout puts all 4 gate types for (batch,unit) in one lane -> in-lane
// activations, fp32 cell state in registers, h crosses steps via tiny dbuf LDS (f16).
__global__ __launch_bounds__(256)
void lstm_kernel(const void* Wih_f, const void* Whh_f, const void* b_f,
                 const void* Wih_b, const void* Whh_b, const void* b_b,
                 const int* mode_p, const short* toks, float* hout) {
  int bx = blockIdx.x;
  int dir = bx >> 5;
  int b0 = (bx & 31) * MB;
  int t = threadIdx.x;
  int w = t >> 6;        // wave id -> unit group
  int lane = t & 63;
  int l = lane & 15;     // MFMA col (unit-within-group / A-row batch)
  int q = lane >> 4;     // quad
  int mode = *mode_p;
  const void* Wih = dir ? Wih_b : Wih_f;
  const void* Whh = dir ? Whh_b : Whh_f;
  const void* bv  = dir ? b_b   : b_f;

  __shared__ __align__(16) f16 hbuf[2][MB][72];  // stride 72 (144B): 2-way bank alias = free
  __shared__ short tok_s[SS * MB];               // [pos][m]

  // preload tokens (coalesced global read, transposed LDS write)
  for (int idx = t; idx < MB * SS; idx += 256) {
    int m = idx >> 10, pos = idx & (SS - 1);
    tok_s[pos * MB + m] = toks[(b0 + m) * SS + pos];
  }
  // zero h buffers
  for (int idx = t; idx < 2 * MB * 72; idx += 256)
    ((f16*)hbuf)[idx] = (f16)0.f;

  // B-operand fragments: B[k][n] layout n=lane&15, k=q*8+j
  // kc 0,1: W_hh[g][k];  kc 2: one-hot K-extension -> W_ih[g][i] (i<20) else 0
  f16x8 Bf[4][3];
  float bias_s[4];
#pragma unroll
  for (int tt = 0; tt < 4; ++tt) {
    int g = 64 * tt + 16 * w + l;   // gate row: type tt, unit 16w+l
    bias_s[tt] = ldw(bv, g, mode);
#pragma unroll
    for (int kc = 0; kc < 2; ++kc) {
      f16x8 v;
#pragma unroll
      for (int j = 0; j < 8; ++j)
        v[j] = (f16)ldw(Whh, g * HH + kc * 32 + q * 8 + j, mode);
      Bf[tt][kc] = v;
    }
    f16x8 v2;
#pragma unroll
    for (int j = 0; j < 8; ++j) {
      int i = q * 8 + j;
      v2[j] = (i < NI) ? (f16)ldw(Wih, g * NI + i, mode) : (f16)0.f;
    }
    Bf[tt][2] = v2;
  }
  __syncthreads();

  float c_st[4] = {0.f, 0.f, 0.f, 0.f};
  int p = 0;
  int jj = 16 * w + l;   // unit this lane activates
  for (int s = 0; s < SS; ++s) {
    int pos = dir ? (SS - 1 - s) : s;
    // A fragments: A[m=l][k=q*8+j], h chunks then in-register one-hot chunk
    f16x8 a0 = *(const f16x8*)&hbuf[p][l][q * 8];
    f16x8 a1 = *(const f16x8*)&hbuf[p][l][32 + q * 8];
    int rel = (int)tok_s[pos * MB + l] - q * 8;
    f16x8 a2;
#pragma unroll
    for (int j = 0; j < 8; ++j) a2[j] = (rel == j) ? (f16)1.f : (f16)0.f;

    f32x4 acc[4];
#pragma unroll
    for (int tt = 0; tt < 4; ++tt) {
      f32x4 c0 = {bias_s[tt], bias_s[tt], bias_s[tt], bias_s[tt]};
      c0 = __builtin_amdgcn_mfma_f32_16x16x32_f16(a0, Bf[tt][0], c0, 0, 0, 0);
      c0 = __builtin_amdgcn_mfma_f32_16x16x32_f16(a1, Bf[tt][1], c0, 0, 0, 0);
      c0 = __builtin_amdgcn_mfma_f32_16x16x32_f16(a2, Bf[tt][2], c0, 0, 0, 0);
      acc[tt] = c0;
    }
    // in-lane activations: batch m=4q+r, unit jj; all four gate types in-lane
#pragma unroll
    for (int r = 0; r < 4; ++r) {
      float gi = acc[0][r], gf = acc[1][r], gg = acc[2][r], go = acc[3][r];
      float cv = sigf(gf) * c_st[r] + sigf(gi) * tanhf_(gg);
      c_st[r] = cv;
      float hv = sigf(go) * tanhf_(cv);
      hbuf[p ^ 1][4 * q + r][jj] = (f16)hv;
      if (s == SS - 1)
        hout[(b0 + 4 * q + r) * 128 + dir * 64 + jj] = hv;
    }
    __syncthreads();
    p ^= 1;
  }
}

// ---- conv path + FC head + softmax; 1 block = 1 batch ----
__global__ void head_kernel(const void* conv1_w, const void* conv2_w, const void* conv2_b,
                            const void* fc1_w, const void* fc1_b,
                            const void* fc2_w, const void* fc2_b,
                            const int* mode_p, const short* toks, const int* lens,
                            const float* hout, void* out) {
  int b = blockIdx.x;
  int t = threadIdx.x;  // 128 threads
  int mode = *mode_p;
  __shared__ float c1w[400];
  __shared__ short tok_s[SS];
  __shared__ float avg[80];
  __shared__ float merged[228];
  __shared__ float fc1v[64];

  for (int i = t; i < 400; i += 128) c1w[i] = ldw(conv1_w, i, mode);
  for (int s = t; s < SS; s += 128) tok_s[s] = toks[b * SS + s];
  __syncthreads();

  int len = lens[b];
  int bw = len >> 2;
  if (t < 80) {
    int k = t / 20, cc = t % 20;
    float sum = 0.f;
    for (int s = k * bw; s < (k + 1) * bw; ++s) {
      // faithful torch reshape: c1r[b,s,cc] lives at flat f = s*20+cc of the [20,1024] map
      int f = s * 20 + cc;
      int ch = f >> 10;
      int pos = f & 1023;
      int tk = tok_s[pos];
      if (tk >= 0) sum += c1w[ch * 20 + tk];  // pos >= len -> zero row -> contributes 0
    }
    avg[t] = sum / (float)bw;
  }
  __syncthreads();

  merged[t] = hout[b * 128 + t];  // [h_fw | h_bw]
  if (t < 100) {
    float dot = ldw(conv2_b, t, mode);
#pragma unroll
    for (int q = 0; q < 80; ++q)
      dot += avg[q] * ldw(conv2_w, t * 80 + q, mode);
    merged[128 + t] = dot > 0.f ? dot : 0.f;  // relu
  }
  __syncthreads();

  if (t < 64) {
    float v = ldw(fc1_b, t, mode);
    for (int m = 0; m < 228; ++m)
      v += merged[m] * ldw(fc1_w, t * 228 + m, mode);
    fc1v[t] = v;   // no activation on fc1 per reference
  }
  __syncthreads();

  if (t == 0) {
    float x0 = ldw(fc2_b, 0, mode), x1 = ldw(fc2_b, 1, mode);
    for (int m = 0; m < 64; ++m) {
      x0 += fc1v[m] * ldw(fc2_w, m, mode);
      x1 += fc1v[m] * ldw(fc2_w, 64 + m, mode);
    }
    float mx = fmaxf(x0, x1);
    float e0 = __expf(x0 - mx), e1 = __expf(x1 - mx);
    float inv = 1.f / (e0 + e1);
    if (mode) {
      ((__hip_bfloat16*)out)[b * 2 + 0] = __float2bfloat16(e0 * inv);
      ((__hip_bfloat16*)out)[b * 2 + 1] = __float2bfloat16(e1 * inv);
    } else {
      ((float*)out)[b * 2 + 0] = e0 * inv;
      ((float*)out)[b * 2 + 1] = e1 * inv;
    }
  }
}

extern "C" void kernel_launch(void* const* d_in, const int* in_sizes, int n_in,
                              void* d_out, int out_size, void* d_ws, size_t ws_size,
                              hipStream_t stream) {
  (void)in_sizes; (void)n_in; (void)out_size; (void)ws_size;
  char* ws = (char*)d_ws;
  int*   mode_p = (int*)ws;                                   // 4 B
  int*   lens   = (int*)(ws + 256);                           // 2 KB
  short* toks   = (short*)(ws + 256 + 2048);                  // 1 MB
  float* hout   = (float*)(ws + 256 + 2048 + (size_t)BB * SS * sizeof(short)); // 256 KB

  probe_kernel<<<1, 1, 0, stream>>>(d_in[3], mode_p);
  tok_kernel<<<BB, 256, 0, stream>>>(d_in[0], mode_p, toks, lens);
  lstm_kernel<<<64, 256, 0, stream>>>(d_in[1], d_in[2], d_in[3],
                                      d_in[4], d_in[5], d_in[6],
                                      mode_p, toks, hout);
  head_kernel<<<BB, 128, 0, stream>>>(d_in[7], d_in[8], d_in[9],
                                      d_in[10], d_in[11], d_in[12], d_in[13],
                                      mode_p, toks, lens, hout, d_out);
}

// Round 3
// 686.003 us; speedup vs baseline: 2.3547x; 1.0844x over previous
//
#include <hip/hip_runtime.h>
#include <hip/hip_bf16.h>

#define BB 512
#define SS 1024
#define NI 20
#define HH 64
#define NG 256  // 4*H
#define MB 16   // batches per block

typedef unsigned short u16;
typedef unsigned int u32;
typedef _Float16 f16;
typedef f16 f16x8 __attribute__((ext_vector_type(8)));
typedef float f32x4 __attribute__((ext_vector_type(4)));

__device__ __forceinline__ float bf2f(u16 b) { return __uint_as_float(((u32)b) << 16); }
// mode==1: data is bf16; mode==0: data is fp32
__device__ __forceinline__ float ldw(const void* p, int idx, int mode) {
  return mode ? bf2f(((const u16*)p)[idx]) : ((const float*)p)[idx];
}
__device__ __forceinline__ float frcp(float x) { return __builtin_amdgcn_rcpf(x); }
__device__ __forceinline__ float sigf(float x) { return frcp(1.f + __expf(-x)); }
__device__ __forceinline__ float tanhf_(float x) {
  float e = __expf(2.f * x);           // overflow -> inf -> rcp -> 0 -> +1; underflow -> 0 -> -1
  return 1.f - 2.f * frcp(e + 1.f);
}

// ---- dtype probe (parallel): read b_f (256 elems) as bf16; fp32 data shows wild exponents ----
__global__ void probe_kernel(const void* bvec, int* mode) {
  __shared__ int bad;
  int t = threadIdx.x;
  if (t == 0) bad = 0;
  __syncthreads();
  float v = bf2f(((const u16*)bvec)[t]);
  if (!(fabsf(v) < 1000.0f)) atomicOr(&bad, 1);
  __syncthreads();
  if (t == 0) *mode = bad ? 0 : 1;
}

// ---- tokens + lengths from one-hot input ----
__global__ void tok_kernel(const void* in1, const int* mode_p, short* toks, int* lens) {
  int b = blockIdx.x;
  int t = threadIdx.x;
  int mode = *mode_p;
  int cnt = 0;
  if (mode) {
    for (int q = 0; q < 4; ++q) {
      int s = t + q * 256;
      const u32* r = (const u32*)in1 + (size_t)(b * SS + s) * 10;  // 2 bf16 per u32
      int tok = -1;
#pragma unroll
      for (int w = 0; w < 10; ++w) {
        u32 u = r[w];
        if (u & 0xFFFFu) tok = 2 * w;
        if (u >> 16)     tok = 2 * w + 1;
      }
      toks[b * SS + s] = (short)tok;
      cnt += (tok >= 0);
    }
  } else {
    for (int q = 0; q < 4; ++q) {
      int s = t + q * 256;
      const float4* r = (const float4*)((const float*)in1 + (size_t)(b * SS + s) * 20);
      int tok = -1;
#pragma unroll
      for (int w = 0; w < 5; ++w) {
        float4 u = r[w];
        if (u.x != 0.f) tok = 4 * w;
        if (u.y != 0.f) tok = 4 * w + 1;
        if (u.z != 0.f) tok = 4 * w + 2;
        if (u.w != 0.f) tok = 4 * w + 3;
      }
      toks[b * SS + s] = (short)tok;
      cnt += (tok >= 0);
    }
  }
  __shared__ int red[256];
  red[t] = cnt;
  __syncthreads();
  for (int stp = 128; stp > 0; stp >>= 1) {
    if (t < stp) red[t] += red[t + stp];
    __syncthreads();
  }
  if (t == 0) lens[b] = red[0];
}

// ---- BiLSTM via MFMA, latency-optimized K-loop ----
// Block = (dir, 16-batch tile); wave w owns units 16w..16w+15, all 4 gate types.
// Per step, the h-critical chain is only: ds_read h -> 2-deep MFMA -> act -> ds_write -> barrier.
// Input projection (one-hot A-chunk x W_ih + bias) for step s+1 is prefetched and its MFMA
// issued during step s (depends only on tok), filling the activation stall window.
__global__ __launch_bounds__(256, 2)
void lstm_kernel(const void* Wih_f, const void* Whh_f, const void* b_f,
                 const void* Wih_b, const void* Whh_b, const void* b_b,
                 const int* mode_p, const short* toks, float* hout) {
  int bx = blockIdx.x;
  int dir = bx >> 5;
  int b0 = (bx & 31) * MB;
  int t = threadIdx.x;
  int w = t >> 6;        // wave id -> unit group
  int lane = t & 63;
  int l = lane & 15;     // MFMA col (unit-within-group / A-row batch)
  int q = lane >> 4;     // quad
  int mode = *mode_p;
  const void* Wih = dir ? Wih_b : Wih_f;
  const void* Whh = dir ? Whh_b : Whh_f;
  const void* bv  = dir ? b_b   : b_f;

  __shared__ __align__(16) f16 hbuf[2][MB][72];  // stride 72 f16 = 144B, 16B-aligned rows
  __shared__ short tok_s[SS * MB];               // [pos][m]

  // preload tokens (coalesced global read, transposed LDS write)
  for (int idx = t; idx < MB * SS; idx += 256) {
    int m = idx >> 10, pos = idx & (SS - 1);
    tok_s[pos * MB + m] = toks[(b0 + m) * SS + pos];
  }
  // zero h buffers
  for (int idx = t; idx < 2 * MB * 72; idx += 256)
    ((f16*)hbuf)[idx] = (f16)0.f;

  // B-operand fragments: B[k][n] layout n=lane&15, k=q*8+j
  // kc 0,1: W_hh[g][k];  kc 2: one-hot K-extension -> W_ih[g][i] (i<20) else 0
  f16x8 Bf[4][3];
  float bias_s[4];
#pragma unroll
  for (int tt = 0; tt < 4; ++tt) {
    int g = 64 * tt + 16 * w + l;   // gate row: type tt, unit 16w+l
    bias_s[tt] = ldw(bv, g, mode);
#pragma unroll
    for (int kc = 0; kc < 2; ++kc) {
      f16x8 v;
#pragma unroll
      for (int j = 0; j < 8; ++j)
        v[j] = (f16)ldw(Whh, g * HH + kc * 32 + q * 8 + j, mode);
      Bf[tt][kc] = v;
    }
    f16x8 v2;
#pragma unroll
    for (int j = 0; j < 8; ++j) {
      int i = q * 8 + j;
      v2[j] = (i < NI) ? (f16)ldw(Wih, g * NI + i, mode) : (f16)0.f;
    }
    Bf[tt][2] = v2;
  }
  __syncthreads();

  float c_st[4] = {0.f, 0.f, 0.f, 0.f};
  float hlast[4] = {0.f, 0.f, 0.f, 0.f};
  int jj = 16 * w + l;   // unit this lane activates

  // prologue: input projection for s=0
  f32x4 accA[4];
  {
    int pos0 = dir ? (SS - 1) : 0;
    int rel = (int)tok_s[pos0 * MB + l] - q * 8;
    f16x8 a2;
#pragma unroll
    for (int j = 0; j < 8; ++j) a2[j] = (rel == j) ? (f16)1.f : (f16)0.f;
#pragma unroll
    for (int tt = 0; tt < 4; ++tt) {
      f32x4 bi = {bias_s[tt], bias_s[tt], bias_s[tt], bias_s[tt]};
      accA[tt] = __builtin_amdgcn_mfma_f32_16x16x32_f16(a2, Bf[tt][2], bi, 0, 0, 0);
    }
  }

  int p = 0;
  for (int s = 0; s < SS; ++s) {
    // h-dependent chain: read h, 2-deep MFMA per gate type
    f16x8 a0 = *(const f16x8*)&hbuf[p][l][q * 8];
    f16x8 a1 = *(const f16x8*)&hbuf[p][l][32 + q * 8];
    f32x4 acc[4];
#pragma unroll
    for (int tt = 0; tt < 4; ++tt) {
      f32x4 c0 = __builtin_amdgcn_mfma_f32_16x16x32_f16(a0, Bf[tt][0], accA[tt], 0, 0, 0);
      acc[tt]  = __builtin_amdgcn_mfma_f32_16x16x32_f16(a1, Bf[tt][1], c0, 0, 0, 0);
    }

    // off-path: prefetch tok[s+1], build one-hot, fire input-projection MFMAs for s+1
    {
      int sn = s + 1;
      int posn = (dir ? (SS - 1 - sn) : sn) & (SS - 1);  // s=SS-1 wraps: result unused
      int reln = (int)tok_s[posn * MB + l] - q * 8;
      f16x8 a2n;
#pragma unroll
      for (int j = 0; j < 8; ++j) a2n[j] = (reln == j) ? (f16)1.f : (f16)0.f;
#pragma unroll
      for (int tt = 0; tt < 4; ++tt) {
        f32x4 bi = {bias_s[tt], bias_s[tt], bias_s[tt], bias_s[tt]};
        accA[tt] = __builtin_amdgcn_mfma_f32_16x16x32_f16(a2n, Bf[tt][2], bi, 0, 0, 0);
      }
    }

    // in-lane activations: batch m=4q+r, unit jj; all four gate types in-lane
#pragma unroll
    for (int r = 0; r < 4; ++r) {
      float gi = acc[0][r], gf = acc[1][r], gg = acc[2][r], go = acc[3][r];
      float cv = sigf(gf) * c_st[r] + sigf(gi) * tanhf_(gg);
      c_st[r] = cv;
      float hv = sigf(go) * tanhf_(cv);
      hlast[r] = hv;
      hbuf[p ^ 1][4 * q + r][jj] = (f16)hv;
    }
    __syncthreads();
    p ^= 1;
  }
#pragma unroll
  for (int r = 0; r < 4; ++r)
    hout[(b0 + 4 * q + r) * 128 + dir * 64 + jj] = hlast[r];
}

// ---- conv path + FC head + softmax; 1 block = 1 batch, 256 threads ----
__global__ void head_kernel(const void* conv1_w, const void* conv2_w, const void* conv2_b,
                            const void* fc1_w, const void* fc1_b,
                            const void* fc2_w, const void* fc2_b,
                            const int* mode_p, const short* toks, const int* lens,
                            const float* hout, void* out) {
  int b = blockIdx.x;
  int t = threadIdx.x;  // 256 threads
  int mode = *mode_p;
  __shared__ float c1w[400];
  __shared__ short tok_s[SS];
  __shared__ float pav[2][80];
  __shared__ float avg[80];
  __shared__ float merged[228];
  __shared__ float fc1v[64];

  for (int i = t; i < 400; i += 256) c1w[i] = ldw(conv1_w, i, mode);
  for (int s = t; s < SS; s += 256) tok_s[s] = toks[b * SS + s];
  __syncthreads();

  int len = lens[b];
  int bw = len >> 2;
  if (t < 160) {
    int half = t / 80;
    int u = t - half * 80;
    int k = u / 20, cc = u % 20;
    int start = k * bw, mid = k * bw + (bw >> 1), end = (k + 1) * bw;
    int s0 = half ? mid : start;
    int s1 = half ? end : mid;
    float sum = 0.f;
    for (int s = s0; s < s1; ++s) {
      // faithful torch reshape: c1r[b,s,cc] lives at flat f = s*20+cc of the [20,1024] map
      int f = s * 20 + cc;
      int ch = f >> 10;
      int pos = f & 1023;
      int tk = tok_s[pos];
      if (tk >= 0) sum += c1w[ch * 20 + tk];  // pos >= len -> zero row -> contributes 0
    }
    pav[half][u] = sum;
  }
  __syncthreads();
  if (t < 80) avg[t] = (pav[0][t] + pav[1][t]) / (float)bw;
  __syncthreads();

  if (t < 128) merged[t] = hout[b * 128 + t];  // [h_fw | h_bw]
  if (t >= 128 && t < 228) {
    int o = t - 128;
    float dot = ldw(conv2_b, o, mode);
#pragma unroll
    for (int q = 0; q < 80; ++q)
      dot += avg[q] * ldw(conv2_w, o * 80 + q, mode);
    merged[t] = dot > 0.f ? dot : 0.f;  // relu
  }
  __syncthreads();

  if (t < 64) {
    float v = ldw(fc1_b, t, mode);
    for (int m = 0; m < 228; ++m)
      v += merged[m] * ldw(fc1_w, t * 228 + m, mode);
    fc1v[t] = v;   // no activation on fc1 per reference
  }
  __syncthreads();

  if (t == 0) {
    float x0 = ldw(fc2_b, 0, mode), x1 = ldw(fc2_b, 1, mode);
    for (int m = 0; m < 64; ++m) {
      x0 += fc1v[m] * ldw(fc2_w, m, mode);
      x1 += fc1v[m] * ldw(fc2_w, 64 + m, mode);
    }
    float mx = fmaxf(x0, x1);
    float e0 = __expf(x0 - mx), e1 = __expf(x1 - mx);
    float inv = 1.f / (e0 + e1);
    if (mode) {
      ((__hip_bfloat16*)out)[b * 2 + 0] = __float2bfloat16(e0 * inv);
      ((__hip_bfloat16*)out)[b * 2 + 1] = __float2bfloat16(e1 * inv);
    } else {
      ((float*)out)[b * 2 + 0] = e0 * inv;
      ((float*)out)[b * 2 + 1] = e1 * inv;
    }
  }
}

extern "C" void kernel_launch(void* const* d_in, const int* in_sizes, int n_in,
                              void* d_out, int out_size, void* d_ws, size_t ws_size,
                              hipStream_t stream) {
  (void)in_sizes; (void)n_in; (void)out_size; (void)ws_size;
  char* ws = (char*)d_ws;
  int*   mode_p = (int*)ws;                                   // 4 B
  int*   lens   = (int*)(ws + 256);                           // 2 KB
  short* toks   = (short*)(ws + 256 + 2048);                  // 1 MB
  float* hout   = (float*)(ws + 256 + 2048 + (size_t)BB * SS * sizeof(short)); // 256 KB

  probe_kernel<<<1, 256, 0, stream>>>(d_in[3], mode_p);
  tok_kernel<<<BB, 256, 0, stream>>>(d_in[0], mode_p, toks, lens);
  lstm_kernel<<<64, 256, 0, stream>>>(d_in[1], d_in[2], d_in[3],
                                      d_in[4], d_in[5], d_in[6],
                                      mode_p, toks, hout);
  head_kernel<<<BB, 256, 0, stream>>>(d_in[7], d_in[8], d_in[9],
                                      d_in[10], d_in[11], d_in[12], d_in[13],
                                      mode_p, toks, lens, hout, d_out);
}